// Round 6
// baseline (201172.546 us; speedup 1.0000x reference)
//
#include <hip/hip_runtime.h>

// RNNDetector: 2-layer LSTM (H=64), T=262144 sequential steps + 16-wide head.
// ROUND 1-5 LESSON (counter-verified): VGPR_Count was 84/48 in every round
// because the AMDGPU register allocator TARGETS max occupancy (launch_bounds'
// 2nd arg is only a minimum) and deliberately spills/remats the per-thread
// weight set to scratch; reloading ~192KB/step through L1/L2 = ~2000 cyc/step,
// which matched every measured duration. FIX: amdgpu_waves_per_eu(2,2) pins
// the occupancy target to exactly 2 waves/EU -> 256-VGPR budget AND no
// incentive to spill below it. Grouped 8-operand asm PINs force the weight
// registers simultaneously live (separate per-value PINs were legally
// satisfiable by per-value scratch reloads).
// Geometry (validated in R5): K-shard each dot across 4 lanes.
//   Lane (q,r,g): q=k-shard(2b), r=gate(2b), g=element-group(4b); owns 4 rows
//   (elements 4g..4g+3, gate r) x 16-col chunk (L0) / 32-col chunk of
//   [Wih1|Whh1] (L1), stored COLUMN-major so a v4 accumulator carries 4
//   row-sums. h-chunk reads: 4 b128 (L0) / 8 b128 (L1) per lane.
//   Shard-reduce xor(1),xor(2); gate exchange xor(8),xor(4) (R2-validated).
// 512 thr = 8 waves (L0 waves 0-3 + head, L1 waves 4-7). One barrier/step.
// Pipeline: step s computes h0(s), h1(s-1), out(s-2); h double-buffered.

constexpr int T = 262144;

typedef float v4 __attribute__((ext_vector_type(4)));

__device__ __forceinline__ float rcp_f(float x) { return __builtin_amdgcn_rcpf(x); }

// ONE asm forcing 8 v4 (=32 VGPRs) simultaneously live & non-rematerializable.
#define PINV8(a,b,c,d,e,f,g,h)                                                 \
  asm volatile("" : "+v"(a), "+v"(b), "+v"(c), "+v"(d),                        \
                    "+v"(e), "+v"(f), "+v"(g), "+v"(h))

// column c of a 4-row block: {M[r0][c], M[r0+1][c], M[r0+2][c], M[r0+3][c]}
#define LCOL(name, M, r0, c)                                                   \
  v4 name = { (M)[(r0)*64+(c)], (M)[((r0)+1)*64+(c)],                          \
              (M)[((r0)+2)*64+(c)], (M)[((r0)+3)*64+(c)] }

// acc[row] += block_cols * h_scalars  (4 cols per group, h from one v4)
#define FMAG(acc, Ca, Cb, Cc, Cd, H)                                           \
  { acc += Ca*(H).x; acc += Cb*(H).y; acc += Cc*(H).z; acc += Cd*(H).w; }

#define RED4(acc, d) { acc.x += __shfl_xor(acc.x, d);                          \
                       acc.y += __shfl_xor(acc.y, d);                          \
                       acc.z += __shfl_xor(acc.z, d);                          \
                       acc.w += __shfl_xor(acc.w, d); }

// R2-validated gate algebra, shuffle distances 8 (r^2) and 4 (r^1).
// pre: this lane's gate-r pre-activation for element e. c kept in ALL lanes.
// Returns h (valid where r==3).
__device__ __forceinline__ float gate_update(float pre, int r, float& c) {
  const bool isG = (r == 2);
  float z  = fminf(fmaxf(pre * (isG ? 2.f : 1.f), -30.f), 30.f);
  float ex = __expf(-z);
  float a  = (isG ? (1.f - ex) : 1.f) * rcp_f(1.f + ex);
  float b2 = __shfl_xor(a, 8);          // partner gate r^2
  // r=0: a=i,b2=g | r=1: a=f,b2=o | r=2: a=g,b2=i | r=3: a=o,b2=f
  float fo = (r & 2) ? b2 : a;
  float m1 = (r & 1) ? fo : a;          // r0:i r1:f r2:g r3:f
  float m2 = (r & 1) ? c  : b2;         // r0:g r1:c r2:i r3:c
  float p  = m1 * m2;
  float cn = p + __shfl_xor(p, 4);      // i*g + f*c in all 4 lanes
  c = cn;
  float zz = fminf(fmaxf(cn, -15.f), 15.f);
  float e2 = __expf(-2.f * zz);
  float th = (1.f - e2) * rcp_f(1.f + e2);
  float oo = (r & 2) ? a : b2;          // r==3 holds o
  return oo * th;
}

__global__ __launch_bounds__(512)
__attribute__((amdgpu_waves_per_eu(2, 2)))   // THE fix: RA targets exactly 2
void rnn_fused(                              // waves/EU -> 256-VGPR budget
    const float* __restrict__ y,
    const float* __restrict__ Wih0, const float* __restrict__ Whh0,
    const float* __restrict__ bih0, const float* __restrict__ bhh0,
    const float* __restrict__ Wih1, const float* __restrict__ Whh1,
    const float* __restrict__ bih1, const float* __restrict__ bhh1,
    const float* __restrict__ Wlin, const float* __restrict__ blin,
    float* __restrict__ out)
{
  const int tid  = threadIdx.x;
  const bool isL1 = tid >= 256;
  const int l  = tid & 255;
  const int q  = l & 3;                 // k-shard
  const int r  = (l >> 2) & 3;          // gate 0=i 1=f 2=g 3=o
  const int g  = l >> 4;                // element group 0..15
  const int e  = 4 * g + q;             // this lane's element
  const int jrow = r * 64 + e;          // row for bias lookup
  const int r0 = r * 64 + 4 * g;        // first of the 4 owned rows

  // LDS: h0[2][64] @0, gap, h1[2][64] @136 (8-float skew: disjoint banks)
  __shared__ __align__(16) float smem[272];
  if (tid < 272) smem[tid] = 0.f;
  __syncthreads();

  if (!isL1) {
    // ===== layer 0 (+ head) =====
    const int c0 = 16 * q;
    LCOL(A0, Whh0, r0, c0+0);  LCOL(A1, Whh0, r0, c0+1);
    LCOL(A2, Whh0, r0, c0+2);  LCOL(A3, Whh0, r0, c0+3);
    LCOL(A4, Whh0, r0, c0+4);  LCOL(A5, Whh0, r0, c0+5);
    LCOL(A6, Whh0, r0, c0+6);  LCOL(A7, Whh0, r0, c0+7);
    LCOL(A8, Whh0, r0, c0+8);  LCOL(A9, Whh0, r0, c0+9);
    LCOL(A10, Whh0, r0, c0+10); LCOL(A11, Whh0, r0, c0+11);
    LCOL(A12, Whh0, r0, c0+12); LCOL(A13, Whh0, r0, c0+13);
    LCOL(A14, Whh0, r0, c0+14); LCOL(A15, Whh0, r0, c0+15);
    float bb  = bih0[jrow] + bhh0[jrow];
    float wi0 = Wih0[jrow];
    // head: m = tid>>4, k4 = tid&15 (0 conflicts, validated R4/R5)
    const int hm = tid >> 4, hk = tid & 15;
    v4 WL = *((const v4*)(Wlin + hm * 64) + hk);
    float bl = (hk == 0) ? blin[hm] : 0.f;
    const float* hbase = smem + c0;               // h0 chunk base
    const float* hhead = smem + 136 + 4 * hk;     // head h1 slice
    float c = 0.f;
    float yq0 = y[0], yq1 = y[1], yq2 = y[2], yq3 = y[3];

    #pragma unroll 1
    for (int s = 0; s < T + 2; ++s) {
      const int cur = s & 1, nxt = cur ^ 1;
      PINV8(A0, A1, A2, A3, A4, A5, A6, A7);
      PINV8(A8, A9, A10, A11, A12, A13, A14, A15);
      // ---- head: out(s-2) from h1[cur] ----
      if (s >= 2) {
        v4 hh = *(const v4*)(hhead + cur * 64);
        v4 tt = WL * hh;
        float p2 = (tt.x + tt.y) + (tt.z + tt.w);
        p2 += __shfl_xor(p2, 1);
        p2 += __shfl_xor(p2, 2);
        p2 += __shfl_xor(p2, 4);
        p2 += __shfl_xor(p2, 8);
        if (hk == 0) out[(s - 2) * 16 + hm] = p2 + bl;
      }
      // ---- layer 0: h0(s) from h0[cur], y[s] ----
      if (s < T) {
        float y_nxt = (s + 4 < T) ? y[s + 4] : 0.f;
        const v4* hp = (const v4*)(hbase + cur * 64);
        v4 H0 = hp[0], H1 = hp[1], H2 = hp[2], H3 = hp[3];
        v4 acc = {0.f,0.f,0.f,0.f}, ac2 = {0.f,0.f,0.f,0.f};
        FMAG(acc, A0, A1, A2, A3, H0);
        FMAG(ac2, A4, A5, A6, A7, H1);
        FMAG(acc, A8, A9, A10, A11, H2);
        FMAG(ac2, A12, A13, A14, A15, H3);
        acc += ac2;
        RED4(acc, 1); RED4(acc, 2);                // sum shards q
        float s1 = (q & 1) ? acc.y : acc.x;
        float s2 = (q & 1) ? acc.w : acc.z;
        float pre = ((q & 2) ? s2 : s1) + fmaf(yq0, wi0, bb);
        float h = gate_update(pre, r, c);
        if (r == 3) smem[nxt * 64 + e] = h;
        yq0 = yq1; yq1 = yq2; yq2 = yq3; yq3 = y_nxt;
      }
      __syncthreads();
    }
  } else {
    // ===== layer 1 =====
    // chunk q of [Wih1 | Whh1] columns: q<2 -> Wih1, q>=2 -> Whh1
    const float* M = (q < 2) ? Wih1 : Whh1;
    const int c0 = 32 * (q & 1);
    LCOL(B0, M, r0, c0+0);   LCOL(B1, M, r0, c0+1);
    LCOL(B2, M, r0, c0+2);   LCOL(B3, M, r0, c0+3);
    LCOL(B4, M, r0, c0+4);   LCOL(B5, M, r0, c0+5);
    LCOL(B6, M, r0, c0+6);   LCOL(B7, M, r0, c0+7);
    LCOL(B8, M, r0, c0+8);   LCOL(B9, M, r0, c0+9);
    LCOL(B10, M, r0, c0+10); LCOL(B11, M, r0, c0+11);
    LCOL(B12, M, r0, c0+12); LCOL(B13, M, r0, c0+13);
    LCOL(B14, M, r0, c0+14); LCOL(B15, M, r0, c0+15);
    LCOL(B16, M, r0, c0+16); LCOL(B17, M, r0, c0+17);
    LCOL(B18, M, r0, c0+18); LCOL(B19, M, r0, c0+19);
    LCOL(B20, M, r0, c0+20); LCOL(B21, M, r0, c0+21);
    LCOL(B22, M, r0, c0+22); LCOL(B23, M, r0, c0+23);
    LCOL(B24, M, r0, c0+24); LCOL(B25, M, r0, c0+25);
    LCOL(B26, M, r0, c0+26); LCOL(B27, M, r0, c0+27);
    LCOL(B28, M, r0, c0+28); LCOL(B29, M, r0, c0+29);
    LCOL(B30, M, r0, c0+30); LCOL(B31, M, r0, c0+31);
    float bb = bih1[jrow] + bhh1[jrow];
    // h operand chunk: q=0: h0[0:32), q=1: h0[32:64), q=2: h1[0:32), q=3: h1[32:64)
    const float* hbase = ((q < 2) ? smem : smem + 136) + 32 * (q & 1);
    float c = 0.f;

    #pragma unroll 1
    for (int s = 0; s < T + 2; ++s) {
      const int cur = s & 1, nxt = cur ^ 1;
      PINV8(B0,  B1,  B2,  B3,  B4,  B5,  B6,  B7);
      PINV8(B8,  B9,  B10, B11, B12, B13, B14, B15);
      PINV8(B16, B17, B18, B19, B20, B21, B22, B23);
      PINV8(B24, B25, B26, B27, B28, B29, B30, B31);
      // ---- layer 1: h1(s-1) from h0[cur]=h0(s-1), h1[cur]=h1(s-2) ----
      if (s >= 1 && s <= T) {
        const v4* hp = (const v4*)(hbase + cur * 64);
        v4 H0 = hp[0], H1 = hp[1], H2 = hp[2], H3 = hp[3];
        v4 H4 = hp[4], H5 = hp[5], H6 = hp[6], H7 = hp[7];
        v4 acc = {0.f,0.f,0.f,0.f}, ac2 = {0.f,0.f,0.f,0.f};
        FMAG(acc, B0,  B1,  B2,  B3,  H0);
        FMAG(ac2, B4,  B5,  B6,  B7,  H1);
        FMAG(acc, B8,  B9,  B10, B11, H2);
        FMAG(ac2, B12, B13, B14, B15, H3);
        FMAG(acc, B16, B17, B18, B19, H4);
        FMAG(ac2, B20, B21, B22, B23, H5);
        FMAG(acc, B24, B25, B26, B27, H6);
        FMAG(ac2, B28, B29, B30, B31, H7);
        acc += ac2;
        RED4(acc, 1); RED4(acc, 2);                // sum 4 shards = full 128-K
        float s1 = (q & 1) ? acc.y : acc.x;
        float s2 = (q & 1) ? acc.w : acc.z;
        float pre = ((q & 2) ? s2 : s1) + bb;
        float h = gate_update(pre, r, c);
        if (r == 3) smem[136 + nxt * 64 + e] = h;
      }
      __syncthreads();
    }
  }
}

extern "C" void kernel_launch(void* const* d_in, const int* in_sizes, int n_in,
                              void* d_out, int out_size, void* d_ws, size_t ws_size,
                              hipStream_t stream) {
  const float* y    = (const float*)d_in[0];
  const float* Wih0 = (const float*)d_in[1];
  const float* Whh0 = (const float*)d_in[2];
  const float* bih0 = (const float*)d_in[3];
  const float* bhh0 = (const float*)d_in[4];
  const float* Wih1 = (const float*)d_in[5];
  const float* Whh1 = (const float*)d_in[6];
  const float* bih1 = (const float*)d_in[7];
  const float* bhh1 = (const float*)d_in[8];
  const float* Wlin = (const float*)d_in[9];
  const float* blin = (const float*)d_in[10];

  rnn_fused<<<dim3(1), dim3(512), 0, stream>>>(
      y, Wih0, Whh0, bih0, bhh0, Wih1, Whh1, bih1, bhh1, Wlin, blin,
      (float*)d_out);
}